// Round 7
// baseline (150.205 us; speedup 1.0000x reference)
//
#include <hip/hip_runtime.h>

#define N_NODES_C   524288
#define N_EDGES_C   786432
#define NUM_GRAPHS_C 8192
#define NT 16          // NUM_NODE_TYPES
#define NODE_DIM_C 256
#define EDGE_DIM_C 128
#define HDIM 384       // NODE_DIM + EDGE_DIM
#define KC 48          // folded inner dim: 16 (node) + 32 (edge)

// R17: fat edge waves. Edge wave = (4 consecutive graphs, slice); lane =
// g'(2b)*16 + p*8 + slot*4 + quad. Per-wave fixed cost (desc load, reduce,
// store) amortized 4x; desc is slice-major (desc[slice][g]) so one wave's 4
// descs are a contiguous 64-B run. Edge blocks 16384 -> 4096.
// Retained from R14/R16 (counter-proven): XCD slicing (slice = idx>>16,
// blk%8 == slice == XCD heuristic, correctness-independent), per-graph
// record compaction with LDS-only atomics, NO global atomics (em8 slice
// partials, folded in k3), node-first dispatch priming each XCD's L2.
#define KR_GRAPH_BLOCKS 2048
#define KR_FOLD_BLOCKS  72
#define KR_BLOCKS (KR_GRAPH_BLOCKS + KR_FOLD_BLOCKS)
#define NODE_BLOCKS 2048           // slice-aligned: blk&7 = slice octant
#define EDGE_BLOCKS 4096           // wave = (4 graphs, slice); blk%8 = slice
#define EDGE_BASE   NODE_BLOCKS    // 2048 % 8 == 0
#define KM_BLOCKS   (NODE_BLOCKS + EDGE_BLOCKS)

// ---------------- workspace layout (bytes, 64-aligned) ----------------
#define WS_NM    0                  // float[8192*16]        512 KB
#define WS_EM8   524288             // float[8192][8][32]    8 MB
#define WS_WC    8912896            // float[48*384]         73728 B
#define WS_NS    8986624            // int[8193]
#define WS_DESC  9019456            // int4[8][8192]         1 MB (slice-major)
#define WS_ECNT  10068032           // int[8192]
#define WS_REC   10100800           // int[1572864]          6 MB

__device__ __forceinline__ void f4_add(float4& a, const float4 v) {
    a.x += v.x; a.y += v.y; a.z += v.z; a.w += v.w;
}

__device__ __forceinline__ void f4_shfl_xor_add(float4& a, int mask) {
    a.x += __shfl_xor(a.x, mask, 64);
    a.y += __shfl_xor(a.y, mask, 64);
    a.z += __shfl_xor(a.z, mask, 64);
    a.w += __shfl_xor(a.w, mask, 64);
}

__device__ __forceinline__ int lower_bound_i32(const int* __restrict__ a, int n, int key) {
    int lo = 0, hi = n;
    while (lo < hi) {
        int mid = (lo + hi) >> 1;
        if (a[mid] < key) lo = mid + 1; else hi = mid;
    }
    return lo;
}

// In-wave segment bounds: lanes 0-31 chase start(g), lanes 32-63 chase end(g)
// concurrently, then shuffle-broadcast (R0-verified).
__device__ __forceinline__ void wave_seg_bounds(const int* __restrict__ b, int n,
                                                int g, int lane, int& s, int& e) {
    int key = g + ((lane >= 32) ? 1 : 0);
    int lo = lower_bound_i32(b, n, key);
    s = __shfl(lo, 0, 64);
    e = __shfl(lo, 32, 64);
}

// kr: fused prep. blocks [0,2048): per-graph record build; [2048,+72): Wc fold.
//  Graph block (4 waves, 1 graph/wave): thread i node-boundary-detect -> nstart;
//  wave: in-wave bsearch of bedge -> (s,e); LDS histogram into 16
//  (slice,endpoint) bins; in-wave scan; desc int4 per slice (slice-major);
//  LDS-cursor record placement into graph-private region [2s,2e) of rec.
//  No global atomics.
__global__ __launch_bounds__(256) void kr_build(
    const int* __restrict__ bnode, const int* __restrict__ bedge,
    const int* __restrict__ esrc, const int* __restrict__ edst,
    const float* __restrict__ Wn, const float* __restrict__ We,
    const float* __restrict__ W1,
    int* __restrict__ rec, int4* __restrict__ desc,
    int* __restrict__ ecnt, int* __restrict__ nstart, float* __restrict__ Wc) {
    int tid = threadIdx.x, blk = blockIdx.x;

    if (blk >= KR_GRAPH_BLOCKS) {
        // ---- weight fold ----
        int o = (blk - KR_GRAPH_BLOCKS) * 256 + tid;    // 0..18431 (= KC*HDIM)
        if (o >= KC * HDIM) return;
        int k = o / HDIM, j = o % HDIM;
        float acc = 0.f;
        if (k < NT) {
            const float* wr = &Wn[k * NODE_DIM_C];
            #pragma unroll 16
            for (int kk = 0; kk < NODE_DIM_C; ++kk)
                acc = fmaf(wr[kk], W1[(size_t)kk * HDIM + j], acc);
        } else {
            const float* wr = &We[(k - NT) * EDGE_DIM_C];
            #pragma unroll 16
            for (int kk = 0; kk < EDGE_DIM_C; ++kk)
                acc = fmaf(wr[kk], W1[(size_t)(NODE_DIM_C + kk) * HDIM + j], acc);
        }
        Wc[o] = acc;
        return;
    }

    int i = blk * 256 + tid;
    {   // node segment bounds (2048*256 threads cover N_NODES exactly)
        int g0 = bnode[i];
        int hi = (i + 1 < N_NODES_C) ? bnode[i + 1] : NUM_GRAPHS_C;
        if (i == 0) for (int g = 0; g <= g0; ++g) nstart[g] = 0;
        for (int g = g0 + 1; g <= hi; ++g) nstart[g] = i + 1;
    }

    int wave = tid >> 6, lane = tid & 63;
    int g = blk * 4 + wave;
    int s, e;
    wave_seg_bounds(bedge, N_EDGES_C, g, lane, s, e);
    int cnt = e - s;
    if (lane == 0) ecnt[g] = cnt;

    __shared__ int lcnt[4][16];
    __shared__ int lcur[4][16];
    if (lane < 16) lcnt[wave][lane] = 0;        // wave-lockstep DS ordering
    for (int q = s + lane; q < e; q += 64) {
        int a = esrc[q];
        atomicAdd(&lcnt[wave][((a >> 16) << 1) + 0], 1);
        int b = edst[q];
        atomicAdd(&lcnt[wave][((b >> 16) << 1) + 1], 1);
    }
    int c = (lane < 16) ? lcnt[wave][lane] : 0;
    int incl = c;
    #pragma unroll
    for (int d = 1; d < 16; d <<= 1) {
        int v = __shfl_up(incl, d, 64);
        if (lane >= d) incl += v;
    }
    int excl = incl - c;
    if (lane < 16) lcur[wave][lane] = excl;     // local cursor
    // desc[slice][g] = {src_start, dst_start, dst_end, cnt} (absolute offsets)
    int i0 = (lane < 8) ? 2 * lane : 0;
    int i1 = (lane < 8) ? 2 * lane + 1 : 0;
    int i2 = (lane < 7) ? 2 * lane + 2 : 0;
    int b0 = __shfl(excl, i0, 64);
    int b1 = __shfl(excl, i1, 64);
    int e1 = __shfl(excl, i2, 64);
    if (lane < 8) {
        int e1a = (lane == 7) ? 2 * s + 2 * cnt : 2 * s + e1;
        desc[(size_t)lane * NUM_GRAPHS_C + g] =
            make_int4(2 * s + b0, 2 * s + b1, e1a, cnt);
    }
    for (int q = s + lane; q < e; q += 64) {
        int a = esrc[q];
        int pa = atomicAdd(&lcur[wave][((a >> 16) << 1) + 0], 1);
        rec[2 * s + pa] = a;
        int b = edst[q];
        int pb = atomicAdd(&lcur[wave][((b >> 16) << 1) + 1], 1);
        rec[2 * s + pb] = b;
    }
}

// KM mega-kernel:
//  blocks [0,2048):      node means; blk&7 = slice octant (g>>10) so the
//     sequential h_node stream primes the owning XCD's L2; these 2048 blocks
//     exactly fill 8-blocks/CU residency before any edge block dispatches.
//  blocks [2048,+4096):  edge partials; wave = (4 graphs, slice);
//     lane = g'*16 + p*8 + slot*4 + quad; 4 contiguous slice-major descs;
//     2 slots/list, wave-uniform T = max ceil(len/2); rows L2-local;
//     plain float4 store to em8[g][slice].
__global__ __launch_bounds__(256) void km_mega(
    const float* __restrict__ h_node,
    const int* __restrict__ nstart, const int4* __restrict__ desc,
    const int* __restrict__ rec,
    float* __restrict__ nm, float* __restrict__ em8) {
    int blk  = blockIdx.x;
    int wave = threadIdx.x >> 6;
    int lane = threadIdx.x & 63;
    const float4* h4 = (const float4*)h_node;
    const float4 z4 = make_float4(0.f, 0.f, 0.f, 0.f);

    if (blk < EDGE_BASE) {
        // ---- node means (slice-aligned placement) ----
        int s8 = blk & 7;               // target XCD == slice octant
        int g  = s8 * 1024 + (blk >> 3) * 4 + wave;
        int s = nstart[g], e = nstart[g + 1];
        int row_off = lane >> 2;   // 0..15
        int quad    = lane & 3;    // 0..3
        float4 a0 = z4, a1 = z4;
        int i = s + row_off;
        for (; i + 16 < e; i += 32) {
            float4 v0 = h4[(size_t)i * 4 + quad];
            float4 v1 = h4[(size_t)(i + 16) * 4 + quad];
            f4_add(a0, v0);
            f4_add(a1, v1);
        }
        if (i < e) f4_add(a0, h4[(size_t)i * 4 + quad]);
        f4_add(a0, a1);
        f4_shfl_xor_add(a0, 4);
        f4_shfl_xor_add(a0, 8);
        f4_shfl_xor_add(a0, 16);
        f4_shfl_xor_add(a0, 32);
        if (row_off == 0) {
            float inv = 1.f / fmaxf((float)(e - s), 1.f);
            ((float4*)nm)[(size_t)g * 4 + quad] =
                make_float4(a0.x * inv, a0.y * inv, a0.z * inv, a0.w * inv);
        }
    } else {
        // ---- edge partial sums (fat wave: 4 graphs x 1 slice) ----
        int r     = blk - EDGE_BASE;
        int slice = r & 7;                      // == blk%8 == XCD (heuristic)
        int gp    = lane >> 4;                  // 0..3 graph sub-index
        int g     = (r >> 3) * 16 + wave * 4 + gp;
        int p     = (lane >> 3) & 1;            // 0=src 1=dst
        int slot  = (lane >> 2) & 1;            // 0..1 record slot
        int quad  = lane & 3;                   // 16 B quarter of the 64-B row
        int4 d    = desc[(size_t)slice * NUM_GRAPHS_C + g];  // one 16-B load
        int st = p ? d.y : d.x;
        int en = p ? d.z : d.y;
        // wave-uniform trip count: max list length over the 8 (g',p) lists
        int len = en - st;
        len = max(len, __shfl_xor(len, 8, 64));
        len = max(len, __shfl_xor(len, 16, 64));
        len = max(len, __shfl_xor(len, 32, 64));
        int T = (len + 1) >> 1;                 // 2 slots per list
        float4 acc = z4;
        int i = st + slot;
        int idx = (i < en) ? rec[i] : -1;
        for (int t = 1; t < T; ++t) {
            int i2 = i + 2;
            int nx = (i2 < en) ? rec[i2] : -1;   // prefetch next record
            if (idx >= 0) f4_add(acc, h4[(size_t)idx * 4 + quad]);
            idx = nx; i = i2;
        }
        if (idx >= 0) f4_add(acc, h4[(size_t)idx * 4 + quad]);
        // reduce over slot (lane bit 2)
        f4_shfl_xor_add(acc, 4);
        if (slot == 0) {
            // em8[g][slice] row = 32 floats: quads 0..3 src half, 4..7 dst half
            ((float4*)em8)[((size_t)(g * 8 + slice)) * 8 + p * 4 + quad] = acc;
        }
    }
}

// K3: fused MLP.  f[g] = [nm(g) | (Σ_s em8[g][s]) / ecnt(g)]  (48 dims)
// pred[g] = relu(f[g] @ Wc + b1) . W2 + b2
#define GPB 16
__global__ __launch_bounds__(HDIM) void k3_mlp(
    const float* __restrict__ nm, const float* __restrict__ em8,
    const int* __restrict__ ecnt,
    const float* __restrict__ Wc, const float* __restrict__ b1,
    const float* __restrict__ W2, const float* __restrict__ b2,
    float* __restrict__ pred) {
    int j = threadIdx.x;
    float wc[KC];
    #pragma unroll
    for (int k = 0; k < KC; ++k) wc[k] = Wc[k * HDIM + j];
    float b1j = b1[j], w2j = W2[j], b20 = b2[0];

    __shared__ float fs[GPB][KC];
    __shared__ float part[GPB][6];
    int g0 = blockIdx.x * GPB;
    for (int t = j; t < GPB * KC; t += HDIM) {
        int g = t / KC, k = t % KC;
        int G = g0 + g;
        float val;
        if (k < NT) {
            val = nm[(size_t)G * NT + k];
        } else {
            float ssum = 0.f;
            #pragma unroll
            for (int s = 0; s < 8; ++s)
                ssum += em8[((size_t)(G * 8 + s)) * 32 + (k - NT)];
            val = ssum / fmaxf((float)ecnt[G], 1.f);
        }
        fs[g][k] = val;
    }
    __syncthreads();

    int wave = j >> 6, lane = j & 63;
    for (int g = 0; g < GPB; ++g) {
        float z = b1j;
        #pragma unroll
        for (int k = 0; k < KC; ++k) z = fmaf(fs[g][k], wc[k], z);
        z = fmaxf(z, 0.f);
        float p = z * w2j;
        #pragma unroll
        for (int off = 32; off > 0; off >>= 1) p += __shfl_down(p, off, 64);
        if (lane == 0) part[g][wave] = p;
    }
    __syncthreads();
    if (j < GPB) {
        float sacc = b20;
        #pragma unroll
        for (int w = 0; w < 6; ++w) sacc += part[j][w];
        pred[g0 + j] = sacc;
    }
}

extern "C" void kernel_launch(void* const* d_in, const int* in_sizes, int n_in,
                              void* d_out, int out_size, void* d_ws, size_t ws_size,
                              hipStream_t stream) {
    const float* h_node     = (const float*)d_in[0];
    // d_in[1] = pos_node (unused)
    const int*   batch_node = (const int*)d_in[2];
    const int*   edge_index = (const int*)d_in[3];   // [2, E] row-major
    const int*   batch_edge = (const int*)d_in[4];
    const float* W_node     = (const float*)d_in[5];
    const float* W_edge     = (const float*)d_in[6];
    const float* W1         = (const float*)d_in[7];
    const float* b1         = (const float*)d_in[8];
    const float* W2         = (const float*)d_in[9];
    const float* b2         = (const float*)d_in[10];
    float* pred = (float*)d_out;

    char* ws = (char*)d_ws;
    float* nm     = (float*)(ws + WS_NM);
    float* em8    = (float*)(ws + WS_EM8);
    float* Wc     = (float*)(ws + WS_WC);
    int*   nstart = (int*)(ws + WS_NS);
    int4*  desc   = (int4*)(ws + WS_DESC);
    int*   ecnt   = (int*)(ws + WS_ECNT);
    int*   rec    = (int*)(ws + WS_REC);

    const int* esrc = edge_index;
    const int* edst = edge_index + N_EDGES_C;

    // kr: fused prep (node bounds + record compaction + slice-major desc + fold)
    kr_build<<<KR_BLOCKS, 256, 0, stream>>>(
        batch_node, batch_edge, esrc, edst, W_node, W_edge, W1,
        rec, desc, ecnt, nstart, Wc);
    // KM: slice-aligned node means (2048) then fat-wave edge gather (4096)
    km_mega <<<KM_BLOCKS, 256, 0, stream>>>(
        h_node, nstart, desc, rec, nm, em8);
    // K3: fold partials + normalize + MLP
    k3_mlp  <<<NUM_GRAPHS_C / GPB, HDIM, 0, stream>>>(
        nm, em8, ecnt, Wc, b1, W2, b2, pred);
}

// Round 8
// 149.293 us; speedup vs baseline: 1.0061x; 1.0061x over previous
//
#include <hip/hip_runtime.h>

#define N_NODES_C   524288
#define N_EDGES_C   786432
#define NUM_GRAPHS_C 8192
#define NT 16          // NUM_NODE_TYPES
#define NODE_DIM_C 256
#define EDGE_DIM_C 128
#define HDIM 384       // NODE_DIM + EDGE_DIM
#define KC 48          // folded inner dim: 16 (node) + 32 (edge)

// R18: 3 kernels, zero redundant streaming.
//  kp: per-graph prep FUSED with node means. Graph block placement is
//      slice-aligned (blk&7 = graph octant = XCD owning the graph's h_node
//      rows), so the sequential 32-MB h_node read both computes nm AND primes
//      the owning XCD's L2 for ke. 4-bounds concurrent in-wave bsearch
//      (estart/eend/nstart/nend in one 20-level loop) kills the nstart array.
//      Also: record compaction (LDS-only atomics) + slice desc + Wc fold.
//  ke: pure edge gather (R16-proven thin-wave form), wave = (g, slice),
//      blk%8 = slice = XCD; h_node rows L2-warm from kp; no global atomics;
//      slice partials to em8[g][slice].
//  k3: fold partials + normalize + fused MLP.
#define KP_GRAPH_BLOCKS 2048
#define KP_FOLD_BLOCKS  72
#define KP_BLOCKS (KP_GRAPH_BLOCKS + KP_FOLD_BLOCKS)
#define KE_BLOCKS 16384            // wave = (graph, slice); blk%8 = slice

// ---------------- workspace layout (bytes, 64-aligned) ----------------
#define WS_NM    0                  // float[8192*16]        512 KB
#define WS_EM8   524288             // float[8192][8][32]    8 MB
#define WS_WC    8912896            // float[48*384]         73728 B
#define WS_DESC  8986624            // int4[8192*8]          1 MB (graph-major)
#define WS_ECNT  10035200           // int[8192]
#define WS_REC   10067968           // int[1572864]          6 MB

__device__ __forceinline__ void f4_add(float4& a, const float4 v) {
    a.x += v.x; a.y += v.y; a.z += v.z; a.w += v.w;
}

__device__ __forceinline__ void f4_shfl_xor_add(float4& a, int mask) {
    a.x += __shfl_xor(a.x, mask, 64);
    a.y += __shfl_xor(a.y, mask, 64);
    a.z += __shfl_xor(a.z, mask, 64);
    a.w += __shfl_xor(a.w, mask, 64);
}

__device__ __forceinline__ int lower_bound_i32(const int* __restrict__ a, int n, int key) {
    int lo = 0, hi = n;
    while (lo < hi) {
        int mid = (lo + hi) >> 1;
        if (a[mid] < key) lo = mid + 1; else hi = mid;
    }
    return lo;
}

// kp: fused prep. blocks [0,2048): graph blocks; [2048,+72): Wc fold.
//  Graph block (slice-aligned): s8 = blk&7, 4 graphs g = s8*1024+(blk>>3)*4+w.
//  Per wave: 4-bounds bsearch -> (es,ee,ns,ne); node means over rows [ns,ne);
//  LDS histogram of edges into 16 (slice,endpoint) bins; in-wave scan; desc;
//  LDS-cursor record placement into [2*es, 2*ee). No global atomics.
__global__ __launch_bounds__(256) void kp_build(
    const int* __restrict__ bnode, const int* __restrict__ bedge,
    const int* __restrict__ esrc, const int* __restrict__ edst,
    const float* __restrict__ h_node,
    const float* __restrict__ Wn, const float* __restrict__ We,
    const float* __restrict__ W1,
    int* __restrict__ rec, int4* __restrict__ desc, int* __restrict__ ecnt,
    float* __restrict__ nm, float* __restrict__ Wc) {
    int tid = threadIdx.x, blk = blockIdx.x;

    if (blk >= KP_GRAPH_BLOCKS) {
        // ---- weight fold ----
        int o = (blk - KP_GRAPH_BLOCKS) * 256 + tid;    // 0..18431 (= KC*HDIM)
        if (o >= KC * HDIM) return;
        int k = o / HDIM, j = o % HDIM;
        float acc = 0.f;
        if (k < NT) {
            const float* wr = &Wn[k * NODE_DIM_C];
            #pragma unroll 16
            for (int kk = 0; kk < NODE_DIM_C; ++kk)
                acc = fmaf(wr[kk], W1[(size_t)kk * HDIM + j], acc);
        } else {
            const float* wr = &We[(k - NT) * EDGE_DIM_C];
            #pragma unroll 16
            for (int kk = 0; kk < EDGE_DIM_C; ++kk)
                acc = fmaf(wr[kk], W1[(size_t)(NODE_DIM_C + kk) * HDIM + j], acc);
        }
        Wc[o] = acc;
        return;
    }

    int wave = tid >> 6, lane = tid & 63;
    int s8 = blk & 7;                       // graph octant == owning XCD
    int g  = s8 * 1024 + (blk >> 3) * 4 + wave;
    const float4* h4 = (const float4*)h_node;
    const float4 z4 = make_float4(0.f, 0.f, 0.f, 0.f);

    // 4-bounds concurrent bsearch: lane groups chase estart/eend/nstart/nend
    {
        const int* arr = (lane & 32) ? bnode : bedge;
        int n   = (lane & 32) ? N_NODES_C : N_EDGES_C;
        int key = g + ((lane >> 4) & 1);
        int lo = lower_bound_i32(arr, n, key);
        __shared__ int bb[4][4];
        if ((lane & 15) == 0) bb[wave][lane >> 4] = lo;
    }
    __builtin_amdgcn_s_waitcnt(0);          // LDS writes visible in-wave
    __shared__ int bbx[4][4];
    // (re-declare trick not allowed; do it properly below)
    int es, ee, ns, ne;
    {
        // redo via shuffles (cheaper than LDS round-trip): every lane has lo
        const int* arr = (lane & 32) ? bnode : bedge;
        int n   = (lane & 32) ? N_NODES_C : N_EDGES_C;
        int key = g + ((lane >> 4) & 1);
        int lo = lower_bound_i32(arr, n, key);
        es = __shfl(lo, 0, 64);
        ee = __shfl(lo, 16, 64);
        ns = __shfl(lo, 32, 64);
        ne = __shfl(lo, 48, 64);
    }
    int cnt = ee - es;
    if (lane == 0) ecnt[g] = cnt;

    // ---- node means (sequential stream, primes own XCD's L2) ----
    {
        int row_off = lane >> 2;   // 0..15
        int quad    = lane & 3;    // 0..3
        float4 a0 = z4, a1 = z4;
        int i = ns + row_off;
        for (; i + 16 < ne; i += 32) {
            float4 v0 = h4[(size_t)i * 4 + quad];
            float4 v1 = h4[(size_t)(i + 16) * 4 + quad];
            f4_add(a0, v0);
            f4_add(a1, v1);
        }
        if (i < ne) f4_add(a0, h4[(size_t)i * 4 + quad]);
        f4_add(a0, a1);
        f4_shfl_xor_add(a0, 4);
        f4_shfl_xor_add(a0, 8);
        f4_shfl_xor_add(a0, 16);
        f4_shfl_xor_add(a0, 32);
        if (row_off == 0) {
            float inv = 1.f / fmaxf((float)(ne - ns), 1.f);
            ((float4*)nm)[(size_t)g * 4 + quad] =
                make_float4(a0.x * inv, a0.y * inv, a0.z * inv, a0.w * inv);
        }
    }

    // ---- record compaction (LDS histogram -> scan -> desc -> place) ----
    __shared__ int lcnt[4][16];
    __shared__ int lcur[4][16];
    if (lane < 16) lcnt[wave][lane] = 0;        // wave-lockstep DS ordering
    for (int q = es + lane; q < ee; q += 64) {
        int a = esrc[q];
        atomicAdd(&lcnt[wave][((a >> 16) << 1) + 0], 1);
        int b = edst[q];
        atomicAdd(&lcnt[wave][((b >> 16) << 1) + 1], 1);
    }
    int c = (lane < 16) ? lcnt[wave][lane] : 0;
    int incl = c;
    #pragma unroll
    for (int d = 1; d < 16; d <<= 1) {
        int v = __shfl_up(incl, d, 64);
        if (lane >= d) incl += v;
    }
    int excl = incl - c;
    if (lane < 16) lcur[wave][lane] = excl;     // local cursor
    // desc[(g,slice)] = {src_start, dst_start, dst_end, cnt} (absolute)
    int i0 = (lane < 8) ? 2 * lane : 0;
    int i1 = (lane < 8) ? 2 * lane + 1 : 0;
    int i2 = (lane < 7) ? 2 * lane + 2 : 0;
    int b0 = __shfl(excl, i0, 64);
    int b1 = __shfl(excl, i1, 64);
    int e1 = __shfl(excl, i2, 64);
    if (lane < 8) {
        int e1a = (lane == 7) ? 2 * es + 2 * cnt : 2 * es + e1;
        desc[(g << 3) + lane] = make_int4(2 * es + b0, 2 * es + b1, e1a, cnt);
    }
    for (int q = es + lane; q < ee; q += 64) {
        int a = esrc[q];
        int pa = atomicAdd(&lcur[wave][((a >> 16) << 1) + 0], 1);
        rec[2 * es + pa] = a;
        int b = edst[q];
        int pb = atomicAdd(&lcur[wave][((b >> 16) << 1) + 1], 1);
        rec[2 * es + pb] = b;
    }
}

// ke: edge partial sums (R16-proven thin-wave slice-local gather).
//  wave = (g, slice); blk%8 = slice = XCD (heuristic, correctness-indep);
//  bounds from one int4 desc load; h_node rows L2-warm from kp;
//  plain float4 store to em8[g][slice].
__global__ __launch_bounds__(256) void ke_edge(
    const float* __restrict__ h_node,
    const int4* __restrict__ desc, const int* __restrict__ rec,
    float* __restrict__ em8) {
    int blk  = blockIdx.x;
    int wave = threadIdx.x >> 6;
    int lane = threadIdx.x & 63;
    const float4* h4 = (const float4*)h_node;
    const float4 z4 = make_float4(0.f, 0.f, 0.f, 0.f);

    int slice = blk & 7;                    // == blk%8 == XCD (heuristic)
    int g     = (blk >> 3) * 4 + wave;
    int4 d    = desc[(g << 3) + slice];     // one load: {s0, s1, e1, cnt}
    int slot = lane >> 3;          // 0..7 record slot
    int p    = (lane >> 2) & 1;    // 0=src 1=dst
    int quad = lane & 3;           // 16 B quarter of the 64-B row
    int st = p ? d.y : d.x;
    int en = p ? d.z : d.y;
    int cmax = max(d.y - d.x, d.z - d.y);
    int T = (cmax + 7) >> 3;       // wave-uniform trips, 8 recs/list/iter
    float4 acc = z4;
    int i = st + slot;
    int idx = (i < en) ? rec[i] : -1;
    for (int t = 1; t < T; ++t) {
        int i2 = i + 8;
        int nx = (i2 < en) ? rec[i2] : -1;   // prefetch next record
        if (idx >= 0) f4_add(acc, h4[(size_t)idx * 4 + quad]);
        idx = nx; i = i2;
    }
    if (idx >= 0) f4_add(acc, h4[(size_t)idx * 4 + quad]);
    // reduce over slot (lane bits 3..5)
    f4_shfl_xor_add(acc, 8);
    f4_shfl_xor_add(acc, 16);
    f4_shfl_xor_add(acc, 32);
    if (slot == 0) {
        // em8[g][slice] row = 32 floats: quads 0..3 src half, 4..7 dst half
        ((float4*)em8)[((size_t)(g * 8 + slice)) * 8 + p * 4 + quad] = acc;
    }
}

// K3: fused MLP.  f[g] = [nm(g) | (Σ_s em8[g][s]) / ecnt(g)]  (48 dims)
// pred[g] = relu(f[g] @ Wc + b1) . W2 + b2
#define GPB 16
__global__ __launch_bounds__(HDIM) void k3_mlp(
    const float* __restrict__ nm, const float* __restrict__ em8,
    const int* __restrict__ ecnt,
    const float* __restrict__ Wc, const float* __restrict__ b1,
    const float* __restrict__ W2, const float* __restrict__ b2,
    float* __restrict__ pred) {
    int j = threadIdx.x;
    float wc[KC];
    #pragma unroll
    for (int k = 0; k < KC; ++k) wc[k] = Wc[k * HDIM + j];
    float b1j = b1[j], w2j = W2[j], b20 = b2[0];

    __shared__ float fs[GPB][KC];
    __shared__ float part[GPB][6];
    int g0 = blockIdx.x * GPB;
    for (int t = j; t < GPB * KC; t += HDIM) {
        int g = t / KC, k = t % KC;
        int G = g0 + g;
        float val;
        if (k < NT) {
            val = nm[(size_t)G * NT + k];
        } else {
            float ssum = 0.f;
            #pragma unroll
            for (int s = 0; s < 8; ++s)
                ssum += em8[((size_t)(G * 8 + s)) * 32 + (k - NT)];
            val = ssum / fmaxf((float)ecnt[G], 1.f);
        }
        fs[g][k] = val;
    }
    __syncthreads();

    int wave = j >> 6, lane = j & 63;
    for (int g = 0; g < GPB; ++g) {
        float z = b1j;
        #pragma unroll
        for (int k = 0; k < KC; ++k) z = fmaf(fs[g][k], wc[k], z);
        z = fmaxf(z, 0.f);
        float p = z * w2j;
        #pragma unroll
        for (int off = 32; off > 0; off >>= 1) p += __shfl_down(p, off, 64);
        if (lane == 0) part[g][wave] = p;
    }
    __syncthreads();
    if (j < GPB) {
        float sacc = b20;
        #pragma unroll
        for (int w = 0; w < 6; ++w) sacc += part[j][w];
        pred[g0 + j] = sacc;
    }
}

extern "C" void kernel_launch(void* const* d_in, const int* in_sizes, int n_in,
                              void* d_out, int out_size, void* d_ws, size_t ws_size,
                              hipStream_t stream) {
    const float* h_node     = (const float*)d_in[0];
    // d_in[1] = pos_node (unused)
    const int*   batch_node = (const int*)d_in[2];
    const int*   edge_index = (const int*)d_in[3];   // [2, E] row-major
    const int*   batch_edge = (const int*)d_in[4];
    const float* W_node     = (const float*)d_in[5];
    const float* W_edge     = (const float*)d_in[6];
    const float* W1         = (const float*)d_in[7];
    const float* b1         = (const float*)d_in[8];
    const float* W2         = (const float*)d_in[9];
    const float* b2         = (const float*)d_in[10];
    float* pred = (float*)d_out;

    char* ws = (char*)d_ws;
    float* nm   = (float*)(ws + WS_NM);
    float* em8  = (float*)(ws + WS_EM8);
    float* Wc   = (float*)(ws + WS_WC);
    int4*  desc = (int4*)(ws + WS_DESC);
    int*   ecnt = (int*)(ws + WS_ECNT);
    int*   rec  = (int*)(ws + WS_REC);

    const int* esrc = edge_index;
    const int* edst = edge_index + N_EDGES_C;

    // kp: fused prep (4-bounds bsearch + node means/L2-prime + records + fold)
    kp_build<<<KP_BLOCKS, 256, 0, stream>>>(
        batch_node, batch_edge, esrc, edst, h_node, W_node, W_edge, W1,
        rec, desc, ecnt, nm, Wc);
    // ke: slice-local edge gather (L2-warm rows)
    ke_edge <<<KE_BLOCKS, 256, 0, stream>>>(h_node, desc, rec, em8);
    // k3: fold partials + normalize + MLP
    k3_mlp  <<<NUM_GRAPHS_C / GPB, HDIM, 0, stream>>>(
        nm, em8, ecnt, Wc, b1, W2, b2, pred);
}

// Round 9
// 139.594 us; speedup vs baseline: 1.0760x; 1.0695x over previous
//
#include <hip/hip_runtime.h>

#define N_NODES_C   524288
#define N_EDGES_C   786432
#define NUM_GRAPHS_C 8192
#define NT 16          // NUM_NODE_TYPES
#define NODE_DIM_C 256
#define EDGE_DIM_C 128
#define HDIM 384       // NODE_DIM + EDGE_DIM
#define KC 48          // folded inner dim: 16 (node) + 32 (edge)

// R19 = exact R14 structure (measured best, 143.7 us) + ONE change:
// edge-wave bounds come from a single int4 desc load (precomputed in kr)
// instead of 3-4 dependent cold scalar loads (binoff x3 / estart).
// R14-proven pieces kept verbatim:
//  - k0: boundary-detect segment bounds (no atomics, no bsearch per wave)
//  - kr: per-graph record compaction, LDS-only atomics
//  - km: fold(72) + slice-aligned node means(2048) + edge gather(16384),
//    slice = idx>>16, blk%8 == slice == XCD heuristic (correctness-indep),
//    em8 slice-major plain stores (NO global atomics)
//  - k3: fold 8 slice partials + normalize + fused MLP
#define FOLD_BLOCKS 72             // ceil(KC*HDIM/256)
#define NODE_BLOCKS 2048           // slice-aligned: r&7 = slice octant
#define EDGE_BLOCKS 16384          // wave = (graph, slice); blk%8 = slice
#define NODE_BASE   FOLD_BLOCKS    // 72 % 8 == 0
#define EDGE_BASE   (FOLD_BLOCKS + NODE_BLOCKS)   // 2120 % 8 == 0
#define TOTAL_BLOCKS (FOLD_BLOCKS + NODE_BLOCKS + EDGE_BLOCKS)

// ---------------- workspace layout (bytes, 64-aligned) ----------------
#define WS_NM    0                  // float[8192*16]        512 KB
#define WS_EM8   524288             // float[8][8192][32]    8 MB (slice-major)
#define WS_WC    8912896            // float[48*384]         73728 B
#define WS_ES    8986624            // int[8193]
#define WS_NS    9019456            // int[8193]
#define WS_DESC  9052288            // int4[8192*8]          1 MB (graph-major)
#define WS_REC   10100864           // int[1572864]          6 MB

__device__ __forceinline__ void f4_add(float4& a, const float4 v) {
    a.x += v.x; a.y += v.y; a.z += v.z; a.w += v.w;
}

__device__ __forceinline__ void f4_shfl_xor_add(float4& a, int mask) {
    a.x += __shfl_xor(a.x, mask, 64);
    a.y += __shfl_xor(a.y, mask, 64);
    a.z += __shfl_xor(a.z, mask, 64);
    a.w += __shfl_xor(a.w, mask, 64);
}

// k0: segment starts via boundary detection (batch arrays are sorted).
// estart[g] = first i with bedge[i] >= g; estart[NUM_GRAPHS] = E. Same for nodes.
__global__ __launch_bounds__(256) void k0_prep(
    const int* __restrict__ bnode, const int* __restrict__ bedge,
    int* __restrict__ estart, int* __restrict__ nstart) {
    int i = blockIdx.x * 256 + threadIdx.x;
    if (i < N_EDGES_C) {
        int g0 = bedge[i];
        int hi = (i + 1 < N_EDGES_C) ? bedge[i + 1] : NUM_GRAPHS_C;
        if (i == 0) for (int g = 0; g <= g0; ++g) estart[g] = 0;
        for (int g = g0 + 1; g <= hi; ++g) estart[g] = i + 1;
    }
    if (i < N_NODES_C) {
        int g0 = bnode[i];
        int hi = (i + 1 < N_NODES_C) ? bnode[i + 1] : NUM_GRAPHS_C;
        if (i == 0) for (int g = 0; g <= g0; ++g) nstart[g] = 0;
        for (int g = g0 + 1; g <= hi; ++g) nstart[g] = i + 1;
    }
}

// kr: per-graph record build, one wave per graph, LDS-only atomics.
// Pass 1: histogram the graph's ~96 edges into 16 (slice,endpoint) bins.
// In-wave scan of 16 counts -> desc int4 per slice {src_start, dst_start,
// dst_end, cnt} (absolute record offsets) + LDS cursors.
// Pass 2: place each endpoint's node index at its bin cursor (graph-private
// region [2s,2e) of rec).
__global__ __launch_bounds__(256) void kr_build(
    const int* __restrict__ esrc, const int* __restrict__ edst,
    const int* __restrict__ estart,
    int* __restrict__ rec, int4* __restrict__ desc) {
    int wave = threadIdx.x >> 6, lane = threadIdx.x & 63;
    int g = blockIdx.x * 4 + wave;
    int s = estart[g], e = estart[g + 1];
    int cnt = e - s;
    __shared__ int lcnt[4][16];
    __shared__ int lcur[4][16];
    if (lane < 16) lcnt[wave][lane] = 0;      // wave-lockstep DS ordering
    for (int i = s + lane; i < e; i += 64) {
        int a = esrc[i];
        atomicAdd(&lcnt[wave][((a >> 16) << 1) + 0], 1);
        int b = edst[i];
        atomicAdd(&lcnt[wave][((b >> 16) << 1) + 1], 1);
    }
    int c = (lane < 16) ? lcnt[wave][lane] : 0;
    int incl = c;
    #pragma unroll
    for (int d = 1; d < 16; d <<= 1) {
        int v = __shfl_up(incl, d, 64);
        if (lane >= d) incl += v;
    }
    int excl = incl - c;
    if (lane < 16) lcur[wave][lane] = excl;   // local cursor
    // desc[(g,slice)] = {src_start, dst_start, dst_end, cnt} (absolute)
    int i0 = (lane < 8) ? 2 * lane : 0;
    int i1 = (lane < 8) ? 2 * lane + 1 : 0;
    int i2 = (lane < 7) ? 2 * lane + 2 : 0;
    int b0 = __shfl(excl, i0, 64);
    int b1 = __shfl(excl, i1, 64);
    int e1 = __shfl(excl, i2, 64);
    if (lane < 8) {
        int e1a = (lane == 7) ? 2 * s + 2 * cnt : 2 * s + e1;
        desc[(g << 3) + lane] = make_int4(2 * s + b0, 2 * s + b1, e1a, cnt);
    }
    for (int i = s + lane; i < e; i += 64) {
        int a = esrc[i];
        int pa = atomicAdd(&lcur[wave][((a >> 16) << 1) + 0], 1);
        rec[2 * s + pa] = a;
        int b = edst[i];
        int pb = atomicAdd(&lcur[wave][((b >> 16) << 1) + 1], 1);
        rec[2 * s + pb] = b;
    }
}

// KM mega-kernel:
//  blocks [0,72):             Wc fold: Wc[k][j] = embedder_row(k) . W1 col j.
//  blocks [NODE_BASE,+2048):  node means; r&7 = slice octant (g>>10) so the
//     sequential h_node stream primes the owning XCD's L2.
//  blocks [EDGE_BASE,+16384): edge partials; wave = (g, slice); bounds from
//     ONE int4 desc load; rows L2-local; plain float4 store to em8[slice][g].
__global__ __launch_bounds__(256) void km_mega(
    const float* __restrict__ h_node,
    const int* __restrict__ nstart, const int4* __restrict__ desc,
    const int* __restrict__ rec,
    const float* __restrict__ Wn, const float* __restrict__ We,
    const float* __restrict__ W1,
    float* __restrict__ nm, float* __restrict__ em8, float* __restrict__ Wc) {
    int blk  = blockIdx.x;
    int wave = threadIdx.x >> 6;
    int lane = threadIdx.x & 63;
    const float4* h4 = (const float4*)h_node;
    const float4 z4 = make_float4(0.f, 0.f, 0.f, 0.f);

    if (blk < FOLD_BLOCKS) {
        // ---- weight fold ----
        int o = blk * 256 + threadIdx.x;        // 0..18431 (= KC*HDIM)
        if (o >= KC * HDIM) return;
        int k = o / HDIM, j = o % HDIM;
        float acc = 0.f;
        if (k < NT) {
            const float* wr = &Wn[k * NODE_DIM_C];
            #pragma unroll 16
            for (int kk = 0; kk < NODE_DIM_C; ++kk)
                acc = fmaf(wr[kk], W1[(size_t)kk * HDIM + j], acc);
        } else {
            const float* wr = &We[(k - NT) * EDGE_DIM_C];
            #pragma unroll 16
            for (int kk = 0; kk < EDGE_DIM_C; ++kk)
                acc = fmaf(wr[kk], W1[(size_t)(NODE_DIM_C + kk) * HDIM + j], acc);
        }
        Wc[o] = acc;
    } else if (blk < EDGE_BASE) {
        // ---- node means (slice-aligned placement) ----
        int r = blk - NODE_BASE;
        int s8 = r & 7;                 // target XCD == slice octant
        int g  = s8 * 1024 + (r >> 3) * 4 + wave;
        int s = nstart[g], e = nstart[g + 1];
        int row_off = lane >> 2;   // 0..15
        int quad    = lane & 3;    // 0..3
        float4 a0 = z4, a1 = z4;
        int i = s + row_off;
        for (; i + 16 < e; i += 32) {
            float4 v0 = h4[(size_t)i * 4 + quad];
            float4 v1 = h4[(size_t)(i + 16) * 4 + quad];
            f4_add(a0, v0);
            f4_add(a1, v1);
        }
        if (i < e) f4_add(a0, h4[(size_t)i * 4 + quad]);
        f4_add(a0, a1);
        f4_shfl_xor_add(a0, 4);
        f4_shfl_xor_add(a0, 8);
        f4_shfl_xor_add(a0, 16);
        f4_shfl_xor_add(a0, 32);
        if (row_off == 0) {
            float inv = 1.f / fmaxf((float)(e - s), 1.f);
            ((float4*)nm)[(size_t)g * 4 + quad] =
                make_float4(a0.x * inv, a0.y * inv, a0.z * inv, a0.w * inv);
        }
    } else {
        // ---- edge partial sums (compacted slice-local gather) ----
        int r     = blk - EDGE_BASE;
        int slice = r & 7;                      // == blk%8 == XCD (heuristic)
        int g     = (r >> 3) * 4 + wave;
        int4 d    = desc[(g << 3) + slice];     // ONE load: {s0, s1, e1, cnt}
        int slot = lane >> 3;          // 0..7 record slot
        int p    = (lane >> 2) & 1;    // 0=src 1=dst
        int quad = lane & 3;           // 16 B quarter of the 64-B row
        int st = p ? d.y : d.x;
        int en = p ? d.z : d.y;
        int cmax = max(d.y - d.x, d.z - d.y);
        int T = (cmax + 7) >> 3;       // wave-uniform trips, 8 recs/list/iter
        float4 acc = z4;
        int i = st + slot;
        int idx = (i < en) ? rec[i] : -1;
        for (int t = 1; t < T; ++t) {
            int i2 = i + 8;
            int nx = (i2 < en) ? rec[i2] : -1;   // prefetch next record
            if (idx >= 0) f4_add(acc, h4[(size_t)idx * 4 + quad]);
            idx = nx; i = i2;
        }
        if (idx >= 0) f4_add(acc, h4[(size_t)idx * 4 + quad]);
        // reduce over slot (lane bits 3..5)
        f4_shfl_xor_add(acc, 8);
        f4_shfl_xor_add(acc, 16);
        f4_shfl_xor_add(acc, 32);
        if (slot == 0) {
            // em8[slice][g] row = 32 floats: quads 0..3 src half, 4..7 dst half
            ((float4*)em8)[((size_t)(slice * NUM_GRAPHS_C + g)) * 8 + p * 4 + quad] = acc;
        }
    }
}

// K3: fused MLP.  f[g] = [nm(g) | (Σ_s em8[s][g]) / ecnt(g)]  (48 dims)
// pred[g] = relu(f[g] @ Wc + b1) . W2 + b2
#define GPB 16
__global__ __launch_bounds__(HDIM) void k3_mlp(
    const float* __restrict__ nm, const float* __restrict__ em8,
    const int* __restrict__ estart,
    const float* __restrict__ Wc, const float* __restrict__ b1,
    const float* __restrict__ W2, const float* __restrict__ b2,
    float* __restrict__ pred) {
    int j = threadIdx.x;
    float wc[KC];
    #pragma unroll
    for (int k = 0; k < KC; ++k) wc[k] = Wc[k * HDIM + j];
    float b1j = b1[j], w2j = W2[j], b20 = b2[0];

    __shared__ float fs[GPB][KC];
    __shared__ float part[GPB][6];
    int g0 = blockIdx.x * GPB;
    for (int t = j; t < GPB * KC; t += HDIM) {
        int g = t / KC, k = t % KC;
        int G = g0 + g;
        float val;
        if (k < NT) {
            val = nm[(size_t)G * NT + k];
        } else {
            float ssum = 0.f;
            #pragma unroll
            for (int s = 0; s < 8; ++s)
                ssum += em8[((size_t)(s * NUM_GRAPHS_C + G)) * 32 + (k - NT)];
            float ec = (float)(estart[G + 1] - estart[G]);
            val = ssum / fmaxf(ec, 1.f);
        }
        fs[g][k] = val;
    }
    __syncthreads();

    int wave = j >> 6, lane = j & 63;
    for (int g = 0; g < GPB; ++g) {
        float z = b1j;
        #pragma unroll
        for (int k = 0; k < KC; ++k) z = fmaf(fs[g][k], wc[k], z);
        z = fmaxf(z, 0.f);
        float p = z * w2j;
        #pragma unroll
        for (int off = 32; off > 0; off >>= 1) p += __shfl_down(p, off, 64);
        if (lane == 0) part[g][wave] = p;
    }
    __syncthreads();
    if (j < GPB) {
        float sacc = b20;
        #pragma unroll
        for (int w = 0; w < 6; ++w) sacc += part[j][w];
        pred[g0 + j] = sacc;
    }
}

extern "C" void kernel_launch(void* const* d_in, const int* in_sizes, int n_in,
                              void* d_out, int out_size, void* d_ws, size_t ws_size,
                              hipStream_t stream) {
    const float* h_node     = (const float*)d_in[0];
    // d_in[1] = pos_node (unused)
    const int*   batch_node = (const int*)d_in[2];
    const int*   edge_index = (const int*)d_in[3];   // [2, E] row-major
    const int*   batch_edge = (const int*)d_in[4];
    const float* W_node     = (const float*)d_in[5];
    const float* W_edge     = (const float*)d_in[6];
    const float* W1         = (const float*)d_in[7];
    const float* b1         = (const float*)d_in[8];
    const float* W2         = (const float*)d_in[9];
    const float* b2         = (const float*)d_in[10];
    float* pred = (float*)d_out;

    char* ws = (char*)d_ws;
    float* nm     = (float*)(ws + WS_NM);
    float* em8    = (float*)(ws + WS_EM8);
    float* Wc     = (float*)(ws + WS_WC);
    int*   estart = (int*)(ws + WS_ES);
    int*   nstart = (int*)(ws + WS_NS);
    int4*  desc   = (int4*)(ws + WS_DESC);
    int*   rec    = (int*)(ws + WS_REC);

    const int* esrc = edge_index;
    const int* edst = edge_index + N_EDGES_C;

    // k0: segment bounds (no atomics)
    k0_prep <<<3072, 256, 0, stream>>>(batch_node, batch_edge, estart, nstart);
    // kr: per-graph compaction + desc, wave/graph, LDS-only atomics
    kr_build<<<NUM_GRAPHS_C / 4, 256, 0, stream>>>(esrc, edst, estart, rec, desc);
    // KM: fold (72) + slice-aligned node means (2048) + compacted edge gather (16384)
    km_mega <<<TOTAL_BLOCKS, 256, 0, stream>>>(
        h_node, nstart, desc, rec, W_node, W_edge, W1, nm, em8, Wc);
    // K3: fold partials + normalize + MLP
    k3_mlp  <<<NUM_GRAPHS_C / GPB, HDIM, 0, stream>>>(
        nm, em8, estart, Wc, b1, W2, b2, pred);
}